// Round 4
// baseline (421.864 us; speedup 1.0000x reference)
//
#include <hip/hip_runtime.h>
#include <stdint.h>

typedef float f32x4 __attribute__((ext_vector_type(4)));
typedef short s16x8 __attribute__((ext_vector_type(8)));
typedef unsigned u32x4 __attribute__((ext_vector_type(4)));

#define B_SZ 256
#define A_RG 196
#define DVD  2048
#define RNN  1024
#define H_SZ 512
#define M_TOT (B_SZ * A_RG)   // 50176 flat rows
#define BM 128
#define BK 32
#define KTILES (DVD / BK)     // 64

__device__ __forceinline__ unsigned short f2bf(float f) {
    unsigned u = __builtin_bit_cast(unsigned, f);
    u = u + 0x7FFFu + ((u >> 16) & 1u);   // RNE
    return (unsigned short)(u >> 16);
}

__device__ __forceinline__ unsigned cvt2(float a, float b) {
    unsigned r;
    asm("v_cvt_pk_bf16_f32 %0, %1, %2" : "=v"(r) : "v"(a), "v"(b));
    return r;
}

__device__ __forceinline__ void gll16(const void* g, void* l) {
    __builtin_amdgcn_global_load_lds(
        (const __attribute__((address_space(1))) void*)g,
        (__attribute__((address_space(3))) void*)l, 16, 0, 0);
}

// ---------------------------------------------------------------------------
// Kernel 1: W_v [2048,512] fp32 -> Wt [512,2048] bf16, transposed AND
// pre-swizzled: within each 64B (32-k) group, chunk c (8 bf16) stored at
// c ^ ((col>>1)&3). Linear global_load_lds staging then lands the tile in
// LDS exactly in the XOR-swizzled layout the fragment reads expect.
// ---------------------------------------------------------------------------
__global__ __launch_bounds__(256) void k_prepW(const float* __restrict__ Wv,
                                               unsigned short* __restrict__ Wt) {
    __shared__ float tile[64][65];
    int kt = blockIdx.x >> 3, ct = blockIdx.x & 7;
    int k0 = kt * 64, c0 = ct * 64;
    int t = threadIdx.x;
    int cl = t & 63, rq = t >> 6;
#pragma unroll
    for (int i = 0; i < 16; ++i) {
        int r = rq * 16 + i;
        tile[r][cl] = Wv[(size_t)(k0 + r) * H_SZ + c0 + cl];
    }
    __syncthreads();
    int kl = t & 63;
#pragma unroll
    for (int i = 0; i < 16; ++i) {
        int cr = rq * 16 + i;
        int col = c0 + cr;
        int s = (col >> 1) & 3;
        int k = k0 + kl;
        int kswz = (k & ~31) | ((((k >> 3) & 3) ^ s) << 3) | (k & 7);
        Wt[(size_t)col * DVD + kswz] = f2bf(tile[kl][cr]);
    }
}

// ---------------------------------------------------------------------------
// Kernel 2: base[b,h] = h_att[b]@W_ha + prev_h2[b]@W_hv + b_ha + b_hv + b_v
// ---------------------------------------------------------------------------
__global__ __launch_bounds__(256) void k_base(const float* __restrict__ h_att,
                                              const float* __restrict__ prev_h2,
                                              const float* __restrict__ W_ha,
                                              const float* __restrict__ b_ha,
                                              const float* __restrict__ W_hv,
                                              const float* __restrict__ b_hv,
                                              const float* __restrict__ b_v,
                                              float* __restrict__ base_g) {
    __shared__ float ha_s[4][RNN];
    __shared__ float pv_s[4][RNN];
    int bg = blockIdx.x >> 2, hg = blockIdx.x & 3;
    int t = threadIdx.x;
#pragma unroll
    for (int i = 0; i < 16; ++i) {
        int idx = i * 256 + t;
        int bl = idx >> 10, k = idx & 1023;
        ha_s[bl][k] = h_att[(size_t)(bg * 4 + bl) * RNN + k];
        pv_s[bl][k] = prev_h2[(size_t)(bg * 4 + bl) * RNN + k];
    }
    __syncthreads();
    int h = hg * 128 + (t & 127);
    int br = t >> 7;
    float aA0 = 0, aA1 = 0, aV0 = 0, aV1 = 0;
#pragma unroll 4
    for (int k = 0; k < RNN; ++k) {
        float w1 = W_ha[(size_t)k * H_SZ + h];
        float w2 = W_hv[(size_t)k * H_SZ + h];
        aA0 = fmaf(ha_s[br * 2][k],     w1, aA0);
        aA1 = fmaf(ha_s[br * 2 + 1][k], w1, aA1);
        aV0 = fmaf(pv_s[br * 2][k],     w2, aV0);
        aV1 = fmaf(pv_s[br * 2 + 1][k], w2, aV1);
    }
    float bias = b_ha[h] + b_hv[h] + b_v[h];
    base_g[(size_t)(bg * 4 + br * 2) * H_SZ + h]     = aA0 + aV0 + bias;
    base_g[(size_t)(bg * 4 + br * 2 + 1) * H_SZ + h] = aA1 + aV1 + bias;
}

// ---------------------------------------------------------------------------
// Kernel 3: flat-M GEMM [50176,2048]x[2048,512] -> fused relu(.+base)*W_f
// reduce. Block 512 = 8 waves (2M x 4N, wave 64x128, acc[4][8] = 128 AGPR).
// Staging purely via global_load_lds (A fp32 source-inverse-swizzled,
// B pre-swizzled in Wt). Counted vmcnt(6), raw barriers, setprio (T3/T4/T5).
// A converted fp32->bf16 at fragment read via v_cvt_pk_bf16_f32.
// ---------------------------------------------------------------------------
__global__ __launch_bounds__(512, 2) void k_gemm(const float* __restrict__ imgs,
                                                 const unsigned short* __restrict__ Wt,
                                                 const float* __restrict__ base_g,
                                                 const float* __restrict__ W_f,
                                                 float* __restrict__ att_g) {
    __shared__ __align__(16) float A_s[2][BM * BK];     // 2 x 16 KB fp32, swizzled
    __shared__ __align__(16) short B_s[2][H_SZ * BK];   // 2 x 32 KB bf16, swizzled
    __shared__ float wf_s[H_SZ];
    __shared__ float base_s[2][H_SZ];
    __shared__ float att_part[4][BM];

    int m0 = blockIdx.x * BM;
    int t = threadIdx.x;
    int lane = t & 63, w = t >> 6;
    int b0 = m0 / A_RG;

    wf_s[t] = W_f[t];
    base_s[0][t] = base_g[(size_t)b0 * H_SZ + t];
    int b1 = min(b0 + 1, B_SZ - 1);
    base_s[1][t] = base_g[(size_t)b1 * H_SZ + t];
    asm volatile("" ::: "memory");   // keep these loads/stores above the pipeline

    // ---- staging descriptors ----
    // A: instr i in {0,1}: LDS linear 1KB slab (w*2+i); lane l -> row
    // r=(w*2+i)*8 + (l>>3), chunk perm (l&7)^(l>>3) (inverse of read swizzle).
    const char* pA[2];
    unsigned ldsA[2];
#pragma unroll
    for (int i = 0; i < 2; ++i) {
        int r = (w * 2 + i) * 8 + (lane >> 3);
        int ch = (lane & 7) ^ (lane >> 3);
        pA[i] = (const char*)(imgs + (size_t)(m0 + r) * DVD) + ch * 16;
        ldsA[i] = (unsigned)(w * 2 + i) * 1024;
    }
    // B: instr i in {0..3}: col=(w*4+i)*16 + (l>>2), chunk l&3 (linear;
    // swizzle pre-baked into Wt by k_prepW).
    const char* pB[4];
    unsigned ldsB[4];
#pragma unroll
    for (int i = 0; i < 4; ++i) {
        int c = (w * 4 + i) * 16 + (lane >> 2);
        pB[i] = (const char*)(Wt + (size_t)c * DVD) + (lane & 3) * 16;
        ldsB[i] = (unsigned)(w * 4 + i) * 1024;
    }

    auto stage = [&](int buf, int kt) {
        char* Ab = (char*)A_s[buf];
        char* Bb = (char*)B_s[buf];
#pragma unroll
        for (int i = 0; i < 2; ++i)
            gll16(pA[i] + (size_t)kt * 128, Ab + ldsA[i]);
#pragma unroll
        for (int i = 0; i < 4; ++i)
            gll16(pB[i] + (size_t)kt * 64, Bb + ldsB[i]);
    };

    // ---- fragment read addresses ----
    int wm = w >> 2, wn = w & 3;
    int lr = lane & 15, g = lane >> 4;
    unsigned aLo[4], aHi[4], bAddr[8];
#pragma unroll
    for (int m = 0; m < 4; ++m) {
        int r = wm * 64 + m * 16 + lr;
        unsigned base = (unsigned)(r * 128 + g * 32);
        unsigned sw = (unsigned)(r & 7) << 4;
        aLo[m] = base ^ sw;
        aHi[m] = (base + 16) ^ sw;
    }
#pragma unroll
    for (int n = 0; n < 8; ++n) {
        int c = wn * 128 + n * 16 + lr;
        bAddr[n] = (unsigned)((c * 64 + g * 16) ^ (((c >> 1) & 3) << 4));
    }

    f32x4 acc[4][8] = {};

    auto compute = [&](int buf) {
        const char* Ac = (const char*)A_s[buf];
        const char* Bc = (const char*)B_s[buf];
        s16x8 bfr[8];
#pragma unroll
        for (int n = 0; n < 8; ++n) bfr[n] = *(const s16x8*)(Bc + bAddr[n]);
        s16x8 afr[4];
#pragma unroll
        for (int m = 0; m < 4; ++m) {
            f32x4 lo = *(const f32x4*)(Ac + aLo[m]);
            f32x4 hi = *(const f32x4*)(Ac + aHi[m]);
            u32x4 p;
            p[0] = cvt2(lo[0], lo[1]);
            p[1] = cvt2(lo[2], lo[3]);
            p[2] = cvt2(hi[0], hi[1]);
            p[3] = cvt2(hi[2], hi[3]);
            afr[m] = __builtin_bit_cast(s16x8, p);
        }
        __builtin_amdgcn_s_setprio(1);
#pragma unroll
        for (int m = 0; m < 4; ++m)
#pragma unroll
            for (int n = 0; n < 8; ++n)
                acc[m][n] = __builtin_amdgcn_mfma_f32_16x16x32_bf16(afr[m], bfr[n], acc[m][n], 0, 0, 0);
        __builtin_amdgcn_s_setprio(0);
    };

    // ---- pipelined K loop: 2-deep, counted vmcnt, raw barriers ----
    stage(0, 0);
    stage(1, 1);
    for (int kt = 0; kt < KTILES - 2; ++kt) {
        asm volatile("s_waitcnt vmcnt(6)" ::: "memory");  // buf[kt&1] landed; next tile's 6 in flight
        __builtin_amdgcn_s_barrier();
        compute(kt & 1);
        asm volatile("" ::: "memory");
        __builtin_amdgcn_s_barrier();                     // all reads of buf[kt&1] retired
        stage(kt & 1, kt + 2);
    }
    asm volatile("s_waitcnt vmcnt(6)" ::: "memory");
    __builtin_amdgcn_s_barrier();
    compute((KTILES - 2) & 1);
    asm volatile("s_waitcnt vmcnt(0)" ::: "memory");
    __builtin_amdgcn_s_barrier();
    compute((KTILES - 1) & 1);

    // ---- epilogue: att[row] = sum_h relu(p + base[b(row),h]) * W_f[h] ----
#pragma unroll
    for (int m = 0; m < 4; ++m) {
        float pj[4] = {0.f, 0.f, 0.f, 0.f};
#pragma unroll
        for (int n = 0; n < 8; ++n) {
            int col = wn * 128 + n * 16 + lr;
            float wfv = wf_s[col];
            f32x4 a4 = acc[m][n];
#pragma unroll
            for (int j = 0; j < 4; ++j) {
                int row = wm * 64 + m * 16 + g * 4 + j;
                int bi = (m0 + row) / A_RG - b0;     // 0 or 1
                pj[j] += fmaxf(a4[j] + base_s[bi][col], 0.f) * wfv;
            }
        }
#pragma unroll
        for (int j = 0; j < 4; ++j) {
            float s = pj[j];
            s += __shfl_xor(s, 1);
            s += __shfl_xor(s, 2);
            s += __shfl_xor(s, 4);
            s += __shfl_xor(s, 8);    // sum over 16 lanes sharing this row
            if (lr == 0) {
                int row = wm * 64 + m * 16 + g * 4 + j;
                att_part[wn][row] = s;    // unique writer per (wn,row)
            }
        }
    }
    __syncthreads();

    if (t < BM) {
        att_g[m0 + t] = att_part[0][t] + att_part[1][t] + att_part[2][t] + att_part[3][t];
    }
}

// ---------------------------------------------------------------------------
// Kernel 4: softmax over A=196 + weighted sum. One block per b, 1024 threads
// (16 waves/CU), thread t owns cols {2t, 2t+1}.
// ---------------------------------------------------------------------------
__global__ __launch_bounds__(1024) void k_ws(const float* __restrict__ imgs,
                                             const float* __restrict__ att_g,
                                             float* __restrict__ out) {
    __shared__ float alpha_s[A_RG];
    int b = blockIdx.x;
    int t = threadIdx.x;

    if (t < 64) {
        float v[4], e[4];
        float mx = -1e30f;
#pragma unroll
        for (int i = 0; i < 4; ++i) {
            int r = i * 64 + t;
            v[i] = (r < A_RG) ? att_g[(size_t)b * A_RG + r] : -1e30f;
            mx = fmaxf(mx, v[i]);
        }
        for (int d = 1; d < 64; d <<= 1) mx = fmaxf(mx, __shfl_xor(mx, d));
        float sum = 0.f;
#pragma unroll
        for (int i = 0; i < 4; ++i) {
            int r = i * 64 + t;
            e[i] = (r < A_RG) ? __expf(v[i] - mx) : 0.f;
            sum += e[i];
        }
        for (int d = 1; d < 64; d <<= 1) sum += __shfl_xor(sum, d);
        float inv = 1.0f / sum;
#pragma unroll
        for (int i = 0; i < 4; ++i) {
            int r = i * 64 + t;
            if (r < A_RG) alpha_s[r] = e[i] * inv;
        }
    }
    __syncthreads();

    const float2* ib2 = (const float2*)(imgs + (size_t)b * A_RG * DVD) + t;
    float2 o0 = make_float2(0.f, 0.f), o1 = make_float2(0.f, 0.f);
#pragma unroll 2
    for (int a = 0; a < A_RG; a += 2) {
        float al0 = alpha_s[a], al1 = alpha_s[a + 1];
        float2 v0 = ib2[(size_t)a * (DVD / 2)];
        float2 v1 = ib2[(size_t)(a + 1) * (DVD / 2)];
        o0.x = fmaf(al0, v0.x, o0.x);
        o0.y = fmaf(al0, v0.y, o0.y);
        o1.x = fmaf(al1, v1.x, o1.x);
        o1.y = fmaf(al1, v1.y, o1.y);
    }
    float2 o = make_float2(o0.x + o1.x, o0.y + o1.y);
    ((float2*)out)[(size_t)b * (DVD / 2) + t] = o;
}

// ---------------------------------------------------------------------------
extern "C" void kernel_launch(void* const* d_in, const int* in_sizes, int n_in,
                              void* d_out, int out_size, void* d_ws, size_t ws_size,
                              hipStream_t stream) {
    const float* h_att   = (const float*)d_in[0];
    const float* prev_h2 = (const float*)d_in[1];
    const float* imgs    = (const float*)d_in[2];
    const float* W_v     = (const float*)d_in[3];
    const float* b_v     = (const float*)d_in[4];
    const float* W_ha    = (const float*)d_in[5];
    const float* b_ha    = (const float*)d_in[6];
    const float* W_hv    = (const float*)d_in[7];
    const float* b_hv    = (const float*)d_in[8];
    const float* W_f     = (const float*)d_in[9];
    // d_in[10] = b_f: softmax-invariant additive constant -> unused

    // ws layout: [0,2MB) Wt bf16 [512][2048] (pre-swizzled);
    //            [2MB,+512KB) base fp32 [256][512]; then att fp32 [50176]
    unsigned short* Wt = (unsigned short*)d_ws;
    float* base_g = (float*)((char*)d_ws + (size_t)DVD * H_SZ * 2);
    float* att_g  = (float*)((char*)d_ws + (size_t)DVD * H_SZ * 2 + (size_t)B_SZ * H_SZ * 4);
    float* out = (float*)d_out;

    hipLaunchKernelGGL(k_prepW, dim3(256), dim3(256), 0, stream, W_v, Wt);
    hipLaunchKernelGGL(k_base, dim3(256), dim3(256), 0, stream,
                       h_att, prev_h2, W_ha, b_ha, W_hv, b_hv, b_v, base_g);
    hipLaunchKernelGGL(k_gemm, dim3(M_TOT / BM), dim3(512), 0, stream,
                       imgs, Wt, base_g, W_f, att_g);
    hipLaunchKernelGGL(k_ws, dim3(B_SZ), dim3(1024), 0, stream,
                       imgs, att_g, out);
}